// Round 1
// 97.355 us; speedup vs baseline: 1.0136x; 1.0136x over previous
//
#include <hip/hip_runtime.h>
#include <hip/hip_bf16.h>
#include <math.h>

#define B_ 4096
#define F_ 64
#define A_ 8
#define U_ 32

typedef float f32x4 __attribute__((ext_vector_type(4)));
typedef short bf16x8 __attribute__((ext_vector_type(8)));

// ws layout:
//   [0, 4 MB): frag blob, per (a,j) 8192 B, index (a*64+j):
//     [0,4096):  K B-frags, fragid = kc*2+ut, 64 lanes x 16 B:
//                bf16 K[f = kc*32 + q*8 + jj][u = ut*16 + c]
//     [4096,8192): W B-frags, fragid = ft:
//                bf16 exp(2*K[f = ft*16 + c][u = q*8 + jj])
//   [4 MB, 4 MB + 64 KB): Kd fp32 (bf16-rounded values): [a*64+j][32] = K[j,a][j][u]
#define KD_OFF (4ull << 20)

static __device__ __forceinline__ unsigned int pk_bf16(float lo, float hi) {
    union { __hip_bfloat162 h2; unsigned int u; } cv;
    cv.h2 = __float22bfloat162_rn(make_float2(lo, hi));
    return cv.u;
}
// round fp32 -> bf16 -> fp32 (match what the MFMA actually sees)
static __device__ __forceinline__ float rb(float f) {
    unsigned int u = __float_as_uint(f);
    u += 0x7FFFu + ((u >> 16) & 1u);
    return __uint_as_float(u & 0xFFFF0000u);
}

// ---------------- prep: one block per (a,j); stage 8 KB, emit frags + Kd ----------------
__global__ __launch_bounds__(256) void ife_prep(const float* __restrict__ kern,
                                                unsigned char* __restrict__ ws)
{
    const int bid = blockIdx.x;           // a*64 + j
    const int a = bid >> 6, j = bid & 63;
    const int t = threadIdx.x;
    __shared__ float st[64][36];          // [f][u], pitch 36 (16B-aligned float4 slots)

    const float* src = kern + ((size_t)j * A_ + a) * (F_ * U_);
    {
        const int f = t >> 2, u0 = (t & 3) * 8;
        *(float4*)&st[f][u0]     = *(const float4*)&src[f * U_ + u0];
        *(float4*)&st[f][u0 + 4] = *(const float4*)&src[f * U_ + u0 + 4];
    }
    __syncthreads();

    unsigned char* dst = ws + (size_t)bid * 8192;
    const int fragid = t >> 6, lane = t & 63, q = lane >> 4, c = lane & 15;

    // K B-frag (fragid = kc*2 + ut)
    {
        const int kc = fragid >> 1, ut = fragid & 1;
        const int f0 = kc * 32 + q * 8, u = ut * 16 + c;
        unsigned int w[4];
        #pragma unroll
        for (int i = 0; i < 4; ++i)
            w[i] = pk_bf16(st[f0 + 2 * i][u], st[f0 + 2 * i + 1][u]);
        *(uint4*)(dst + fragid * 1024 + lane * 16) = make_uint4(w[0], w[1], w[2], w[3]);
    }
    // W B-frag (fragid = ft)
    {
        const int f = fragid * 16 + c, u0 = q * 8;
        const float4 wa = *(const float4*)&st[f][u0];
        const float4 wb = *(const float4*)&st[f][u0 + 4];
        unsigned int w[4];
        w[0] = pk_bf16(__expf(2.f * wa.x), __expf(2.f * wa.y));
        w[1] = pk_bf16(__expf(2.f * wa.z), __expf(2.f * wa.w));
        w[2] = pk_bf16(__expf(2.f * wb.x), __expf(2.f * wb.y));
        w[3] = pk_bf16(__expf(2.f * wb.z), __expf(2.f * wb.w));
        *(uint4*)(dst + 4096 + fragid * 1024 + lane * 16) = make_uint4(w[0], w[1], w[2], w[3]);
    }
    // Kd (bf16-rounded so the rank-1 correction exactly cancels the MFMA j-term)
    if (t < U_)
        ((float*)(ws + KD_OFF))[(size_t)bid * U_ + t] = rb(st[j][t]);
}

// ---------------- main: (a, 64-row tile); wave = 16 rows; NO barrier in j-loop ----------------
// Software-pipelined over j: the E (softmax numerator) LDS round-trip for iteration j
// overlaps with the Z-MFMA/exp of iteration j+1. Double-buffered PbufA/PbufB; the
// per-iteration s_waitcnt lgkmcnt(0) drain is gone.
__global__ __launch_bounds__(256, 2) void ife_main(const float* __restrict__ x,
                                                   const unsigned char* __restrict__ ws,
                                                   float* __restrict__ out)
{
    const int a = blockIdx.y, bt = blockIdx.x, t = threadIdx.x;
    const int wv = t >> 6, lane = t & 63, q = lane >> 4, c = lane & 15;

    __shared__ float Xf[64][66];                       // bf16-rounded fp32 X tile
    __shared__ float Kd[64][32];                       // bf16-rounded K[j][j][u] for this a
    __shared__ __align__(16) unsigned int PbufA[4][16][20];  // wave-private E, pitch 20 dwords
    __shared__ __align__(16) unsigned int PbufB[4][16][20];  // double buffer

    // X A-frags (m = c, k = kc*32 + q*8 + jj), pure bf16
    bf16x8 Xh[2];
    {
        const float* xr = x + (size_t)(bt * 64 + wv * 16 + c) * F_;
        #pragma unroll
        for (int kc = 0; kc < 2; ++kc) {
            const float4 va = *(const float4*)&xr[kc * 32 + q * 8];
            const float4 vb = *(const float4*)&xr[kc * 32 + q * 8 + 4];
            union { unsigned int u[4]; bf16x8 v; } H;
            H.u[0] = pk_bf16(va.x, va.y);
            H.u[1] = pk_bf16(va.z, va.w);
            H.u[2] = pk_bf16(vb.x, vb.y);
            H.u[3] = pk_bf16(vb.z, vb.w);
            Xh[kc] = H.v;
        }
    }
    // Xf (bf16-rounded values, fp32 storage, broadcast-friendly)
    {
        const int row = t >> 2, cb = (t & 3) * 16;
        const float* xsrc = x + (size_t)(bt * 64 + row) * F_ + cb;
        #pragma unroll
        for (int i = 0; i < 16; i += 4) {
            const float4 v = *(const float4*)&xsrc[i];
            Xf[row][cb + i]     = rb(v.x);
            Xf[row][cb + i + 1] = rb(v.y);
            Xf[row][cb + i + 2] = rb(v.z);
            Xf[row][cb + i + 3] = rb(v.w);
        }
    }
    // Kd stage (contiguous 8 KB)
    {
        const float* kd = (const float*)(ws + KD_OFF) + (size_t)a * 64 * U_;
        const int jj = t >> 2, u0 = (t & 3) * 8;
        *(float4*)&Kd[jj][u0]     = *(const float4*)&kd[jj * U_ + u0];
        *(float4*)&Kd[jj][u0 + 4] = *(const float4*)&kd[jj * U_ + u0 + 4];
    }
    __syncthreads();   // the only block-wide barrier

    const unsigned int psel = (q < 2) ? 0x05040100u : 0x07060302u;
    const unsigned char* fbase = ws + (size_t)a * 64 * 8192 + (size_t)lane * 16;

    union { unsigned int u[4]; bf16x8 v; } oc;
    oc.u[0] = 0x3F803F80u; oc.u[1] = 0x3F803F80u; oc.u[2] = 0x3F803F80u; oc.u[3] = 0x3F803F80u;
    const bf16x8 ONES = oc.v;
    const f32x4 vzero = (f32x4){0.f, 0.f, 0.f, 0.f};

    f32x4 S0 = vzero, S1 = vzero, S2 = vzero, S3 = vzero;

    bf16x8 KA[4], WA[4], KB[4], WB[4];
    float xjA[4], xjB[4], kdA0, kdA1, kdB0, kdB1;
    uint4 ra0, ra1, rb0, rb1;

    auto LOADF = [&](bf16x8* K, bf16x8* W, int jj) {
        const unsigned char* p = fbase + (size_t)jj * 8192;
        #pragma unroll
        for (int i = 0; i < 4; ++i) {
            K[i] = *(const bf16x8*)(p + i * 1024);
            W[i] = *(const bf16x8*)(p + 4096 + i * 1024);
        }
    };

    // per-j scalars (LDS broadcast reads), prefetched one iteration ahead
    auto SCAL = [&](float* xj, float& k0, float& k1, int j) {
        #pragma unroll
        for (int r = 0; r < 4; ++r) xj[r] = Xf[wv * 16 + q * 4 + r][j];
        k0 = Kd[j][c];
        k1 = Kd[j][16 + c];
    };

    // stage 1: Z = X@K (MFMA), rank-1 mask correction + exp, write unnormalized E to LDS
    auto ZW = [&](const bf16x8* K, const float* xj, float kd0, float kd1,
                  unsigned int (*P)[16][20]) {
        f32x4 ZA = vzero, ZB = vzero;
        ZA = __builtin_amdgcn_mfma_f32_16x16x32_bf16(Xh[0], K[0], ZA, 0, 0, 0);
        ZA = __builtin_amdgcn_mfma_f32_16x16x32_bf16(Xh[1], K[2], ZA, 0, 0, 0);
        ZB = __builtin_amdgcn_mfma_f32_16x16x32_bf16(Xh[0], K[1], ZB, 0, 0, 0);
        ZB = __builtin_amdgcn_mfma_f32_16x16x32_bf16(Xh[1], K[3], ZB, 0, 0, 0);
        #pragma unroll
        for (int r = 0; r < 4; ++r) {
            const float e0 = __expf(ZA[r] - xj[r] * kd0);
            const float e1 = __expf(ZB[r] - xj[r] * kd1);
            P[wv][q * 4 + r][c] = pk_bf16(e0, e1);
        }
    };

    // stage 2a: issue the transposed read-back of E (latency hides under next ZW)
    auto RD = [&](uint4& pa, uint4& pb, const unsigned int (*P)[16][20]) {
        // compile-time ordering fence only (no HW wait): keeps prior ds_writes /
        // later ds_writes from being moved across these cross-lane reads
        asm volatile("" ::: "memory");
        pa = *(const uint4*)&P[wv][c][(q & 1) * 8];
        pb = *(const uint4*)&P[wv][c][(q & 1) * 8 + 4];
    };

    // stage 2b: perm-deinterleave, row sums via MFMA vs ones, PV MFMAs, normalize+accumulate
    auto FN = [&](const uint4& pa, const uint4& pb, const bf16x8* W) {
        union { unsigned int u[4]; bf16x8 v; } E;
        E.u[0] = __builtin_amdgcn_perm(pa.y, pa.x, psel);
        E.u[1] = __builtin_amdgcn_perm(pa.w, pa.z, psel);
        E.u[2] = __builtin_amdgcn_perm(pb.y, pb.x, psel);
        E.u[3] = __builtin_amdgcn_perm(pb.w, pb.z, psel);

        const f32x4 sv = __builtin_amdgcn_mfma_f32_16x16x32_bf16(E.v, ONES, vzero, 0, 0, 0);
        f32x4 D0 = __builtin_amdgcn_mfma_f32_16x16x32_bf16(E.v, W[0], vzero, 0, 0, 0);
        f32x4 D1 = __builtin_amdgcn_mfma_f32_16x16x32_bf16(E.v, W[1], vzero, 0, 0, 0);
        f32x4 D2 = __builtin_amdgcn_mfma_f32_16x16x32_bf16(E.v, W[2], vzero, 0, 0, 0);
        f32x4 D3 = __builtin_amdgcn_mfma_f32_16x16x32_bf16(E.v, W[3], vzero, 0, 0, 0);
        #pragma unroll
        for (int r = 0; r < 4; ++r) {
            const float inv = __builtin_amdgcn_rcpf(sv[r]);
            S0[r] += D0[r] * inv;
            S1[r] += D1[r] * inv;
            S2[r] += D2[r] * inv;
            S3[r] += D3[r] * inv;
        }
    };

    // ---- pipeline ----
    // prologue: Z(0) written to PA; frags/scalars for j=1 staged
    LOADF(KA, WA, 0);
    SCAL(xjA, kdA0, kdA1, 0);
    ZW(KA, xjA, kdA0, kdA1, PbufA);
    LOADF(KB, WB, 1);
    SCAL(xjB, kdB0, kdB1, 1);

    // steady state: body j handles {read E_j, Z(j+1), finish j, read E_{j+1}, Z(j+2), finish j+1}
    for (int j = 0; j < 62; j += 2) {
        RD(ra0, ra1, PbufA);                 // E_j   (written >= half a body ago)
        ZW(KB, xjB, kdB0, kdB1, PbufB);      // Z(j+1) -> PB; hides read latency
        FN(ra0, ra1, WA);                    // finish j (uses W_j in A set)
        LOADF(KA, WA, j + 2);                // frags for j+2 (consumed next half-body)
        SCAL(xjA, kdA0, kdA1, j + 2);
        RD(rb0, rb1, PbufB);                 // E_{j+1}
        ZW(KA, xjA, kdA0, kdA1, PbufA);      // Z(j+2) -> PA
        FN(rb0, rb1, WB);                    // finish j+1
        LOADF(KB, WB, j + 3);                // j <= 60 so j+3 <= 63
        SCAL(xjB, kdB0, kdB1, j + 3);
    }
    // tail: PA holds E_62, B set holds j=63, WA holds W_62
    RD(ra0, ra1, PbufA);
    ZW(KB, xjB, kdB0, kdB1, PbufB);          // Z(63) -> PB
    FN(ra0, ra1, WA);                        // finish 62
    RD(rb0, rb1, PbufB);
    FN(rb0, rb1, WB);                        // finish 63

    // epilogue: mean over j, softmax over f (flat scores -> no max needed)
    const float sc = 1.f / 64.f;
    #pragma unroll
    for (int r = 0; r < 4; ++r) {
        const float e0 = __expf(S0[r] * sc);
        const float e1 = __expf(S1[r] * sc);
        const float e2 = __expf(S2[r] * sc);
        const float e3 = __expf(S3[r] * sc);
        float s = e0 + e1 + e2 + e3;
        s += __shfl_xor(s, 1);
        s += __shfl_xor(s, 2);
        s += __shfl_xor(s, 4);
        s += __shfl_xor(s, 8);
        const float inv = 1.f / s;
        const int b = bt * 64 + wv * 16 + q * 4 + r;
        float* o = out + ((size_t)a * B_ + b) * F_ + c;
        o[0]  = e0 * inv;
        o[16] = e1 * inv;
        o[32] = e2 * inv;
        o[48] = e3 * inv;
    }
}

extern "C" void kernel_launch(void* const* d_in, const int* in_sizes, int n_in,
                              void* d_out, int out_size, void* d_ws, size_t ws_size,
                              hipStream_t stream) {
    (void)in_sizes; (void)n_in; (void)out_size; (void)ws_size;
    const float* x    = (const float*)d_in[0];   // [B, F]
    const float* kern = (const float*)d_in[1];   // [F, A, F, U]
    float* out        = (float*)d_out;           // [A, B, F]
    unsigned char* ws = (unsigned char*)d_ws;    // ~4.1 MB used

    hipLaunchKernelGGL(ife_prep, dim3(F_ * A_), dim3(256), 0, stream, kern, ws);
    hipLaunchKernelGGL(ife_main, dim3(B_ / 64, A_), dim3(256), 0, stream, x, ws, out);
}